// Round 2
// baseline (1106.327 us; speedup 1.0000x reference)
//
#include <hip/hip_runtime.h>
#include <math.h>

#define TT 65536
#define DD 256
#define EE 8
#define HH 512
#define OO 256

typedef unsigned int u32;
typedef unsigned short u16;
typedef __attribute__((ext_vector_type(4))) float f32x4;
typedef __attribute__((ext_vector_type(2))) u32 u32x2;
typedef __attribute__((ext_vector_type(4))) u32 u32x4;
typedef __attribute__((ext_vector_type(8))) __bf16 bf16x8;

__device__ __forceinline__ u16 f2bf(float f) {
    u32 u = __builtin_bit_cast(u32, f);
    u32 r = (u + 0x7fffu + ((u >> 16) & 1u)) >> 16;
    return (u16)r;
}

__device__ __forceinline__ bf16x8 ld_frag(const void* p) {
    u32x4 v = *(const u32x4*)p;
    return __builtin_bit_cast(bf16x8, v);
}

// tanh-form gelu via exp2 + rcp: gelu(v) = v / (1 + exp(-1.5957692*v*(1+0.044715*v^2)))
__device__ __forceinline__ float gelu_fast(float v) {
    float t = v * v;
    float u = __builtin_fmaf(t, -0.1029479f, -2.3022075f);   // -log2(e)*1.5957692*(1+0.044715 t)
    float z = v * u;                                          // z = -log2(e)*1.5958*(v+0.044715 v^3)
    float e = __builtin_amdgcn_exp2f(z);
    return v * __builtin_amdgcn_rcpf(1.0f + e);
}

// ---------------- convert/transpose weights ----------------
// w1 [E][D][H] f32 -> w1t [E][H][D] bf16
__global__ __launch_bounds__(256) void k_conv_w1(const float* __restrict__ w1, u16* __restrict__ w1t) {
    int i = blockIdx.x * 256 + threadIdx.x;            // < E*H*D = 1M
    int d = i & 255, h = (i >> 8) & 511, e = i >> 17;
    w1t[i] = f2bf(w1[((size_t)e << 17) + ((size_t)d << 9) + h]);
}
// w2 [E][H][O] f32 -> w2t [E][O][H] bf16
__global__ __launch_bounds__(256) void k_conv_w2(const float* __restrict__ w2, u16* __restrict__ w2t) {
    int i = blockIdx.x * 256 + threadIdx.x;            // < E*O*H = 1M
    int h = i & 511, o = (i >> 9) & 255, e = i >> 17;
    w2t[i] = f2bf(w2[((size_t)e << 17) + ((size_t)h << 8) + o]);
}

// ---------------- gating: softmax, entropy, top-p mask, weights ----------------
// writes wt TRANSPOSED: wt[e][t]  (coalesced, and k_moe can stage conflict-free)
__global__ __launch_bounds__(256) void k_gating(const float* __restrict__ x,
                                                const float* __restrict__ gw,
                                                const float* __restrict__ gb,
                                                float* __restrict__ wt,
                                                double* __restrict__ part) {
    __shared__ float gws[DD * EE];
    __shared__ float gbs[EE];
    __shared__ double red[256];
    int tid = threadIdx.x;
    for (int i = tid; i < DD * EE; i += 256) gws[i] = gw[i];
    if (tid < EE) gbs[tid] = gb[tid];
    __syncthreads();

    int t = blockIdx.x * 256 + tid;
    double l[EE];
#pragma unroll
    for (int e = 0; e < EE; ++e) l[e] = (double)gbs[e];

    const f32x4* xr = (const f32x4*)(x + (size_t)t * DD);
    for (int d4 = 0; d4 < DD / 4; ++d4) {
        f32x4 xv = xr[d4];
#pragma unroll
        for (int j = 0; j < 4; ++j) {
            double xs = (double)xv[j];
            int d = d4 * 4 + j;
#pragma unroll
            for (int e = 0; e < EE; ++e) l[e] += xs * (double)gws[d * EE + e];
        }
    }
    double mx = l[0];
#pragma unroll
    for (int e = 1; e < EE; ++e) mx = l[e] > mx ? l[e] : mx;
    double p[EE], s = 0.0;
#pragma unroll
    for (int e = 0; e < EE; ++e) { p[e] = exp(l[e] - mx); s += p[e]; }
    double inv = 1.0 / s;
    double ent = 0.0;
#pragma unroll
    for (int e = 0; e < EE; ++e) { p[e] *= inv; ent += p[e] * log(p[e] + 1e-8); }

    // top-p mask (stable descending argsort semantics, no dynamic indexing)
    bool mask[EE];
#pragma unroll
    for (int e = 0; e < EE; ++e) {
        double c = 0.0; int rk = 0;
#pragma unroll
        for (int f = 0; f < EE; ++f) {
            bool before = (p[f] > p[e]) || (p[f] == p[e] && f < e);
            if (before) { c += p[f]; rk++; }
        }
        c += p[e];                       // inclusive cumsum at e's sorted position
        mask[e] = (c <= 0.7) || (rk == 0);
    }
    double ms = 0.0;
#pragma unroll
    for (int e = 0; e < EE; ++e) if (mask[e]) ms += p[e];
    double inv2 = 1.0 / ms;
#pragma unroll
    for (int e = 0; e < EE; ++e) wt[(size_t)e * TT + t] = (float)(mask[e] ? p[e] * inv2 : 0.0);

    red[tid] = -ent;
    __syncthreads();
    for (int st = 128; st > 0; st >>= 1) {
        if (tid < st) red[tid] += red[tid + st];
        __syncthreads();
    }
    if (tid == 0) part[blockIdx.x] = red[0];
}

__global__ __launch_bounds__(256) void k_final(const double* __restrict__ part, float* __restrict__ loss) {
    __shared__ double red[256];
    int tid = threadIdx.x;
    red[tid] = part[tid];
    __syncthreads();
    for (int st = 128; st > 0; st >>= 1) {
        if (tid < st) red[tid] += red[tid + st];
        __syncthreads();
    }
    if (tid == 0) loss[0] = (float)(red[0] / (double)TT);
}

// ---------------- fused MoE MLP ----------------
// 64 tokens/block, 4 waves. Per expert, per 128-wide H-chunk:
//   GEMM1: Hf[h][tok] = X @ W1 (transposed), gelu, *weight -> Hs (bf16, swizzled LDS)
//   GEMM2: oacc[tok][o] += Hs @ W2
// LDS = 32K (Xs) + 16K (Hs) + 2K (wts) = 50K -> 3 blocks/CU
__global__ __launch_bounds__(256, 3) void k_moe(const float* __restrict__ x,
                                                const u16* __restrict__ w1t,
                                                const u16* __restrict__ w2t,
                                                const float* __restrict__ b1,
                                                const float* __restrict__ b2,
                                                const float* __restrict__ wtg,
                                                float* __restrict__ out) {
    __shared__ __align__(16) unsigned char smem[51200];
    unsigned char* Xs = smem;                     // 64 x 256 bf16 (swizzled rows, 512B) = 32768
    unsigned char* Hs = smem + 32768;             // 64 x 128 bf16 (swizzled rows, 256B) = 16384
    float* wts = (float*)(smem + 49152);          // [E][64] f32 = 2048

    const int tid = threadIdx.x;
    const int wid = tid >> 6;
    const int lane = tid & 63;
    const int lr = lane & 15;
    const int lg = lane >> 4;
    const int t0 = blockIdx.x * 64;

    // stage X tile: f32 -> bf16, XOR-swizzled rows (row stride 512B)
    {
        const f32x4* xsrc = (const f32x4*)(x + (size_t)t0 * DD);
#pragma unroll
        for (int i = 0; i < 8; ++i) {
            int L = i * 4096 + tid * 16;          // byte offset in bf16 tile
            f32x4 a = xsrc[L >> 3];
            f32x4 b = xsrc[(L >> 3) + 1];
            u32x4 o;
            o.x = (u32)f2bf(a[0]) | ((u32)f2bf(a[1]) << 16);
            o.y = (u32)f2bf(a[2]) | ((u32)f2bf(a[3]) << 16);
            o.z = (u32)f2bf(b[0]) | ((u32)f2bf(b[1]) << 16);
            o.w = (u32)f2bf(b[2]) | ((u32)f2bf(b[3]) << 16);
            int row = L >> 9;
            *(u32x4*)(Xs + (L ^ ((row & 7) << 4))) = o;
        }
    }
    // stage token weights transposed: wts[e][tok]
#pragma unroll
    for (int i = 0; i < 2; ++i) {
        int e = wid + i * 4;
        wts[e * 64 + lane] = wtg[(size_t)e * TT + t0 + lane];
    }
    __syncthreads();

    f32x4 oacc[4][4];
#pragma unroll
    for (int a = 0; a < 4; ++a)
#pragma unroll
        for (int b = 0; b < 4; ++b) oacc[a][b] = (f32x4)0.0f;

#pragma unroll 1
    for (int e = 0; e < EE; ++e) {
#pragma unroll 1
        for (int ch = 0; ch < 4; ++ch) {
            // ---- GEMM1: wave computes h-rows [wid*32, wid*32+32) of this 128-chunk, all 64 tokens
            f32x4 hf[2][4];
#pragma unroll
            for (int a = 0; a < 2; ++a)
#pragma unroll
                for (int b = 0; b < 4; ++b) hf[a][b] = (f32x4)0.0f;

            const u16* w1p = w1t + (((size_t)e * HH) + ch * 128 + wid * 32) * DD;
#pragma unroll
            for (int kb = 0; kb < 8; ++kb) {
                int krow = kb * 32 + lg * 8;
                bf16x8 af[2], bfr[4];
#pragma unroll
                for (int mb = 0; mb < 2; ++mb)
                    af[mb] = ld_frag(w1p + (size_t)(mb * 16 + lr) * DD + krow);
#pragma unroll
                for (int nb = 0; nb < 4; ++nb) {
                    int tok = nb * 16 + lr;
                    int byt = tok * 512 + krow * 2;
                    bfr[nb] = ld_frag(Xs + (byt ^ ((tok & 7) << 4)));
                }
#pragma unroll
                for (int mb = 0; mb < 2; ++mb)
#pragma unroll
                    for (int nb = 0; nb < 4; ++nb)
                        hf[mb][nb] = __builtin_amdgcn_mfma_f32_16x16x32_bf16(af[mb], bfr[nb], hf[mb][nb], 0, 0, 0);
            }
            // epilogue: +b1, fast gelu, *token weight, pack bf16, write Hs (swizzled, 256B rows)
#pragma unroll
            for (int mb = 0; mb < 2; ++mb) {
                int hl = wid * 32 + mb * 16 + lg * 4;     // h within chunk [0,128)
                f32x4 bb = *(const f32x4*)(b1 + (size_t)e * HH + ch * 128 + hl);
#pragma unroll
                for (int nb = 0; nb < 4; ++nb) {
                    int tok = nb * 16 + lr;
                    float wgt = wts[e * 64 + tok];
                    float g[4];
#pragma unroll
                    for (int r = 0; r < 4; ++r) {
                        float v = hf[mb][nb][r] + bb[r];
                        g[r] = gelu_fast(v) * wgt;
                    }
                    u32x2 pk;
                    pk.x = (u32)f2bf(g[0]) | ((u32)f2bf(g[1]) << 16);
                    pk.y = (u32)f2bf(g[2]) | ((u32)f2bf(g[3]) << 16);
                    int byt = tok * 256 + hl * 2;
                    *(u32x2*)(Hs + (byt ^ ((tok & 7) << 4))) = pk;
                }
            }
            __syncthreads();
            // ---- GEMM2: wave computes o-cols [wid*64, wid*64+64), K = this 128-chunk of H
            const u16* w2p = w2t + ((size_t)e * OO + wid * 64) * HH + ch * 128;
#pragma unroll
            for (int kb = 0; kb < 4; ++kb) {
                int krow = kb * 32 + lg * 8;              // [0,128)
                bf16x8 af[4], bfr[4];
#pragma unroll
                for (int mb = 0; mb < 4; ++mb) {
                    int tok = mb * 16 + lr;
                    int byt = tok * 256 + krow * 2;
                    af[mb] = ld_frag(Hs + (byt ^ ((tok & 7) << 4)));
                }
#pragma unroll
                for (int nb = 0; nb < 4; ++nb)
                    bfr[nb] = ld_frag(w2p + (size_t)(nb * 16 + lr) * HH + krow);
#pragma unroll
                for (int mb = 0; mb < 4; ++mb)
#pragma unroll
                    for (int nb = 0; nb < 4; ++nb)
                        oacc[mb][nb] = __builtin_amdgcn_mfma_f32_16x16x32_bf16(af[mb], bfr[nb], oacc[mb][nb], 0, 0, 0);
            }
            __syncthreads();
        }
    }

    // epilogue: add sum_e w[t][e]*b2[e][o], store
#pragma unroll
    for (int nb = 0; nb < 4; ++nb) {
        int o = wid * 64 + nb * 16 + lr;
        float b2v[EE];
#pragma unroll
        for (int e = 0; e < EE; ++e) b2v[e] = b2[e * OO + o];
#pragma unroll
        for (int mb = 0; mb < 4; ++mb) {
#pragma unroll
            for (int r = 0; r < 4; ++r) {
                int trow = mb * 16 + lg * 4 + r;
                float wb = 0.f;
#pragma unroll
                for (int e = 0; e < EE; ++e) wb += wts[e * 64 + trow] * b2v[e];
                out[(size_t)(t0 + trow) * OO + o] = oacc[mb][nb][r] + wb;
            }
        }
    }
}

extern "C" void kernel_launch(void* const* d_in, const int* in_sizes, int n_in,
                              void* d_out, int out_size, void* d_ws, size_t ws_size,
                              hipStream_t stream) {
    const float* x  = (const float*)d_in[0];
    const float* gw = (const float*)d_in[1];
    const float* gb = (const float*)d_in[2];
    const float* w1 = (const float*)d_in[3];
    const float* b1 = (const float*)d_in[4];
    const float* w2 = (const float*)d_in[5];
    const float* b2 = (const float*)d_in[6];
    float* out = (float*)d_out;

    char* ws = (char*)d_ws;
    u16* w1t    = (u16*)(ws);                    // 2 MB
    u16* w2t    = (u16*)(ws + 2097152);          // 2 MB
    float* wt   = (float*)(ws + 4194304);        // 2 MB ([E][T])
    double* prt = (double*)(ws + 6291456);       // 2 KB

    k_conv_w1<<<(EE * HH * DD) / 256, 256, 0, stream>>>(w1, w1t);
    k_conv_w2<<<(EE * OO * HH) / 256, 256, 0, stream>>>(w2, w2t);
    k_gating<<<TT / 256, 256, 0, stream>>>(x, gw, gb, wt, prt);
    k_moe<<<TT / 64, 256, 0, stream>>>(x, w1t, w2t, b1, b2, wt, out);
    k_final<<<1, 256, 0, stream>>>(prt, out + (size_t)TT * OO);
}

// Round 3
// 818.467 us; speedup vs baseline: 1.3517x; 1.3517x over previous
//
#include <hip/hip_runtime.h>
#include <math.h>

#define TT 65536
#define DD 256
#define EE 8
#define HH 512
#define OO 256

typedef unsigned int u32;
typedef unsigned short u16;
typedef __attribute__((ext_vector_type(4))) float f32x4;
typedef __attribute__((ext_vector_type(2))) u32 u32x2;
typedef __attribute__((ext_vector_type(4))) u32 u32x4;
typedef __attribute__((ext_vector_type(8))) __bf16 bf16x8;

__device__ __forceinline__ u16 f2bf(float f) {
    u32 u = __builtin_bit_cast(u32, f);
    u32 r = (u + 0x7fffu + ((u >> 16) & 1u)) >> 16;
    return (u16)r;
}

__device__ __forceinline__ bf16x8 ld_frag(const void* p) {
    u32x4 v = *(const u32x4*)p;
    return __builtin_bit_cast(bf16x8, v);
}

// tanh-form gelu via exp2 + rcp: gelu(v) = v / (1 + exp(-1.5957692*v*(1+0.044715*v^2)))
__device__ __forceinline__ float gelu_fast(float v) {
    float t = v * v;
    float u = __builtin_fmaf(t, -0.1029479f, -2.3022075f);
    float z = v * u;
    float e = __builtin_amdgcn_exp2f(z);
    return v * __builtin_amdgcn_rcpf(1.0f + e);
}

// ---------------- convert/transpose weights ----------------
__global__ __launch_bounds__(256) void k_conv_w1(const float* __restrict__ w1, u16* __restrict__ w1t) {
    int i = blockIdx.x * 256 + threadIdx.x;            // < E*H*D = 1M
    int d = i & 255, h = (i >> 8) & 511, e = i >> 17;
    w1t[i] = f2bf(w1[((size_t)e << 17) + ((size_t)d << 9) + h]);
}
__global__ __launch_bounds__(256) void k_conv_w2(const float* __restrict__ w2, u16* __restrict__ w2t) {
    int i = blockIdx.x * 256 + threadIdx.x;            // < E*O*H = 1M
    int h = i & 511, o = (i >> 9) & 255, e = i >> 17;
    w2t[i] = f2bf(w2[((size_t)e << 17) + ((size_t)h << 8) + o]);
}

// ---------------- gating ----------------
__global__ __launch_bounds__(256) void k_gating(const float* __restrict__ x,
                                                const float* __restrict__ gw,
                                                const float* __restrict__ gb,
                                                float* __restrict__ wt,
                                                double* __restrict__ part) {
    __shared__ float gws[DD * EE];
    __shared__ float gbs[EE];
    __shared__ double red[256];
    int tid = threadIdx.x;
    for (int i = tid; i < DD * EE; i += 256) gws[i] = gw[i];
    if (tid < EE) gbs[tid] = gb[tid];
    __syncthreads();

    int t = blockIdx.x * 256 + tid;
    double l[EE];
#pragma unroll
    for (int e = 0; e < EE; ++e) l[e] = (double)gbs[e];

    const f32x4* xr = (const f32x4*)(x + (size_t)t * DD);
    for (int d4 = 0; d4 < DD / 4; ++d4) {
        f32x4 xv = xr[d4];
#pragma unroll
        for (int j = 0; j < 4; ++j) {
            double xs = (double)xv[j];
            int d = d4 * 4 + j;
#pragma unroll
            for (int e = 0; e < EE; ++e) l[e] += xs * (double)gws[d * EE + e];
        }
    }
    double mx = l[0];
#pragma unroll
    for (int e = 1; e < EE; ++e) mx = l[e] > mx ? l[e] : mx;
    double p[EE], s = 0.0;
#pragma unroll
    for (int e = 0; e < EE; ++e) { p[e] = exp(l[e] - mx); s += p[e]; }
    double inv = 1.0 / s;
    double ent = 0.0;
#pragma unroll
    for (int e = 0; e < EE; ++e) { p[e] *= inv; ent += p[e] * log(p[e] + 1e-8); }

    bool mask[EE];
#pragma unroll
    for (int e = 0; e < EE; ++e) {
        double c = 0.0; int rk = 0;
#pragma unroll
        for (int f = 0; f < EE; ++f) {
            bool before = (p[f] > p[e]) || (p[f] == p[e] && f < e);
            if (before) { c += p[f]; rk++; }
        }
        c += p[e];
        mask[e] = (c <= 0.7) || (rk == 0);
    }
    double ms = 0.0;
#pragma unroll
    for (int e = 0; e < EE; ++e) if (mask[e]) ms += p[e];
    double inv2 = 1.0 / ms;
#pragma unroll
    for (int e = 0; e < EE; ++e) wt[(size_t)e * TT + t] = (float)(mask[e] ? p[e] * inv2 : 0.0);

    red[tid] = -ent;
    __syncthreads();
    for (int st = 128; st > 0; st >>= 1) {
        if (tid < st) red[tid] += red[tid + st];
        __syncthreads();
    }
    if (tid == 0) part[blockIdx.x] = red[0];
}

__global__ __launch_bounds__(256) void k_final(const double* __restrict__ part, float* __restrict__ loss) {
    __shared__ double red[256];
    int tid = threadIdx.x;
    red[tid] = part[tid];
    __syncthreads();
    for (int st = 128; st > 0; st >>= 1) {
        if (tid < st) red[tid] += red[tid + st];
        __syncthreads();
    }
    if (tid == 0) loss[0] = (float)(red[0] / (double)TT);
}

// ---------------- fused MoE MLP ----------------
// 64 tokens/block, 4 waves. 32 chunks of 128 h (e = c>>2, ch = c&3).
// Pipelined, double-buffered Hs, ONE barrier per chunk:
//   iter c: GEMM1(c+1) compute -> GEMM2(c) from Hs[c&1] -> write Hs[(c+1)&1] -> barrier
// LDS = 32K Xs + 2*16K Hs + 2K wts = 66K -> 2 blocks/CU. No reg cap (avoid r2 spill).
__global__ __launch_bounds__(256) void k_moe(const float* __restrict__ x,
                                             const u16* __restrict__ w1t,
                                             const u16* __restrict__ w2t,
                                             const float* __restrict__ b1,
                                             const float* __restrict__ b2,
                                             const float* __restrict__ wtg,
                                             float* __restrict__ out) {
    __shared__ __align__(16) unsigned char smem[67584];
    unsigned char* Xs = smem;                     // 64 x 512B (bf16, swizzled) = 32768
    // Hs buffers at smem+32768, smem+49152 : 64 x 256B (bf16, swizzled) each
    float* wts = (float*)(smem + 65536);          // [E][64] f32 = 2048

    const int tid = threadIdx.x;
    const int wid = tid >> 6;
    const int lane = tid & 63;
    const int lr = lane & 15;
    const int lg = lane >> 4;
    const int t0 = blockIdx.x * 64;

    // stage X tile: f32 -> bf16, XOR-swizzled rows (row stride 512B)
    {
        const f32x4* xsrc = (const f32x4*)(x + (size_t)t0 * DD);
#pragma unroll
        for (int i = 0; i < 8; ++i) {
            int L = i * 4096 + tid * 16;
            f32x4 a = xsrc[L >> 3];
            f32x4 b = xsrc[(L >> 3) + 1];
            u32x4 o;
            o.x = (u32)f2bf(a[0]) | ((u32)f2bf(a[1]) << 16);
            o.y = (u32)f2bf(a[2]) | ((u32)f2bf(a[3]) << 16);
            o.z = (u32)f2bf(b[0]) | ((u32)f2bf(b[1]) << 16);
            o.w = (u32)f2bf(b[2]) | ((u32)f2bf(b[3]) << 16);
            int row = L >> 9;
            *(u32x4*)(Xs + (L ^ ((row & 7) << 4))) = o;
        }
    }
#pragma unroll
    for (int i = 0; i < 2; ++i) {
        int e = wid + i * 4;
        wts[e * 64 + lane] = wtg[(size_t)e * TT + t0 + lane];
    }
    __syncthreads();

    f32x4 oacc[4][4];
#pragma unroll
    for (int a = 0; a < 4; ++a)
#pragma unroll
        for (int b = 0; b < 4; ++b) oacc[a][b] = (f32x4)0.0f;

    f32x4 hf[2][4];

    // GEMM1 for chunk c: wave computes h rows [wid*32, wid*32+32) of the 128-chunk, 64 tokens
    auto g1 = [&](int c) {
#pragma unroll
        for (int a = 0; a < 2; ++a)
#pragma unroll
            for (int b = 0; b < 4; ++b) hf[a][b] = (f32x4)0.0f;
        const u16* w1p = w1t + (size_t)(c * 128 + wid * 32) * DD;
#pragma unroll
        for (int kb = 0; kb < 8; ++kb) {
            int krow = kb * 32 + lg * 8;
            bf16x8 af[2], bfr[4];
#pragma unroll
            for (int mb = 0; mb < 2; ++mb)
                af[mb] = ld_frag(w1p + (size_t)(mb * 16 + lr) * DD + krow);
#pragma unroll
            for (int nb = 0; nb < 4; ++nb) {
                int tok = nb * 16 + lr;
                int byt = tok * 512 + krow * 2;
                bfr[nb] = ld_frag(Xs + (byt ^ ((tok & 7) << 4)));
            }
#pragma unroll
            for (int mb = 0; mb < 2; ++mb)
#pragma unroll
                for (int nb = 0; nb < 4; ++nb)
                    hf[mb][nb] = __builtin_amdgcn_mfma_f32_16x16x32_bf16(af[mb], bfr[nb], hf[mb][nb], 0, 0, 0);
        }
    };

    // bias+gelu+weight, pack, write chunk c's h into buffer H
    auto hwrite = [&](int c, unsigned char* H) {
        int e = c >> 2;
#pragma unroll
        for (int mb = 0; mb < 2; ++mb) {
            int hl = wid * 32 + mb * 16 + lg * 4;           // h within chunk [0,128)
            f32x4 bb = *(const f32x4*)(b1 + c * 128 + hl);
#pragma unroll
            for (int nb = 0; nb < 4; ++nb) {
                int tok = nb * 16 + lr;
                float wgt = wts[e * 64 + tok];
                float g[4];
#pragma unroll
                for (int r = 0; r < 4; ++r) {
                    float v = hf[mb][nb][r] + bb[r];
                    g[r] = gelu_fast(v) * wgt;
                }
                u32x2 pk;
                pk.x = (u32)f2bf(g[0]) | ((u32)f2bf(g[1]) << 16);
                pk.y = (u32)f2bf(g[2]) | ((u32)f2bf(g[3]) << 16);
                int byt = tok * 256 + hl * 2;
                *(u32x2*)(H + (byt ^ ((tok & 7) << 4))) = pk;
            }
        }
    };

    // GEMM2 for chunk c from buffer H: wave computes o-cols [wid*64, wid*64+64), K = 128
    auto g2 = [&](int c, const unsigned char* H) {
        int e = c >> 2, ch = c & 3;
        const u16* w2p = w2t + ((size_t)(e * OO) + wid * 64) * HH + ch * 128;
#pragma unroll
        for (int kb = 0; kb < 4; ++kb) {
            int krow = kb * 32 + lg * 8;                    // [0,128)
            bf16x8 af[4], bfr[4];
#pragma unroll
            for (int mb = 0; mb < 4; ++mb) {
                int tok = mb * 16 + lr;
                int byt = tok * 256 + krow * 2;
                af[mb] = ld_frag(H + (byt ^ ((tok & 7) << 4)));
            }
#pragma unroll
            for (int nb = 0; nb < 4; ++nb)
                bfr[nb] = ld_frag(w2p + (size_t)(nb * 16 + lr) * HH + krow);
#pragma unroll
            for (int mb = 0; mb < 4; ++mb)
#pragma unroll
                for (int nb = 0; nb < 4; ++nb)
                    oacc[mb][nb] = __builtin_amdgcn_mfma_f32_16x16x32_bf16(af[mb], bfr[nb], oacc[mb][nb], 0, 0, 0);
        }
    };

    // prologue: fill Hs[0] with chunk 0
    g1(0);
    hwrite(0, smem + 32768);
    __syncthreads();

#pragma unroll 1
    for (int c = 0; c < 32; ++c) {
        unsigned char* Hcur = smem + 32768 + ((c & 1) ? 16384 : 0);
        unsigned char* Hnxt = smem + 32768 + ((c & 1) ? 0 : 16384);
        if (c < 31) g1(c + 1);        // compute next chunk's h (regs only)
        g2(c, Hcur);                  // consume current chunk
        if (c < 31) hwrite(c + 1, Hnxt);
        __syncthreads();
    }

    // epilogue: add sum_e w[t][e]*b2[e][o], store
#pragma unroll
    for (int nb = 0; nb < 4; ++nb) {
        int o = wid * 64 + nb * 16 + lr;
        float b2v[EE];
#pragma unroll
        for (int e = 0; e < EE; ++e) b2v[e] = b2[e * OO + o];
#pragma unroll
        for (int mb = 0; mb < 4; ++mb) {
#pragma unroll
            for (int r = 0; r < 4; ++r) {
                int trow = mb * 16 + lg * 4 + r;
                float wb = 0.f;
#pragma unroll
                for (int e = 0; e < EE; ++e) wb += wts[e * 64 + trow] * b2v[e];
                out[(size_t)(t0 + trow) * OO + o] = oacc[mb][nb][r] + wb;
            }
        }
    }
}

extern "C" void kernel_launch(void* const* d_in, const int* in_sizes, int n_in,
                              void* d_out, int out_size, void* d_ws, size_t ws_size,
                              hipStream_t stream) {
    const float* x  = (const float*)d_in[0];
    const float* gw = (const float*)d_in[1];
    const float* gb = (const float*)d_in[2];
    const float* w1 = (const float*)d_in[3];
    const float* b1 = (const float*)d_in[4];
    const float* w2 = (const float*)d_in[5];
    const float* b2 = (const float*)d_in[6];
    float* out = (float*)d_out;

    char* ws = (char*)d_ws;
    u16* w1t    = (u16*)(ws);                    // 2 MB
    u16* w2t    = (u16*)(ws + 2097152);          // 2 MB
    float* wt   = (float*)(ws + 4194304);        // 2 MB ([E][T])
    double* prt = (double*)(ws + 6291456);       // 2 KB

    k_conv_w1<<<(EE * HH * DD) / 256, 256, 0, stream>>>(w1, w1t);
    k_conv_w2<<<(EE * OO * HH) / 256, 256, 0, stream>>>(w2, w2t);
    k_gating<<<TT / 256, 256, 0, stream>>>(x, gw, gb, wt, prt);
    k_moe<<<TT / 64, 256, 0, stream>>>(x, w1t, w2t, b1, b2, wt, out);
    k_final<<<1, 256, 0, stream>>>(prt, out + (size_t)TT * OO);
}

// Round 4
// 544.782 us; speedup vs baseline: 2.0308x; 1.5024x over previous
//
#include <hip/hip_runtime.h>
#include <math.h>

#define TT 65536
#define DD 256
#define EE 8
#define HH 512
#define OO 256

typedef unsigned int u32;
typedef unsigned short u16;
typedef __attribute__((ext_vector_type(4))) float f32x4;
typedef __attribute__((ext_vector_type(16))) float f32x16;
typedef __attribute__((ext_vector_type(2))) u32 u32x2;
typedef __attribute__((ext_vector_type(4))) u32 u32x4;
typedef __attribute__((ext_vector_type(8))) __bf16 bf16x8;

__device__ __forceinline__ u16 f2bf(float f) {
    u32 u = __builtin_bit_cast(u32, f);
    u32 r = (u + 0x7fffu + ((u >> 16) & 1u)) >> 16;
    return (u16)r;
}

__device__ __forceinline__ bf16x8 ld_frag(const void* p) {
    u32x4 v = *(const u32x4*)p;
    return __builtin_bit_cast(bf16x8, v);
}

// tanh-form gelu via exp2 + rcp
__device__ __forceinline__ float gelu_fast(float v) {
    float t = v * v;
    float u = __builtin_fmaf(t, -0.1029479f, -2.3022075f);
    float z = v * u;
    float e = __builtin_amdgcn_exp2f(z);
    return v * __builtin_amdgcn_rcpf(1.0f + e);
}

// ---------------- convert/transpose weights ----------------
__global__ __launch_bounds__(256) void k_conv_w1(const float* __restrict__ w1, u16* __restrict__ w1t) {
    int i = blockIdx.x * 256 + threadIdx.x;            // < E*H*D = 1M
    int d = i & 255, h = (i >> 8) & 511, e = i >> 17;
    w1t[i] = f2bf(w1[((size_t)e << 17) + ((size_t)d << 9) + h]);
}
__global__ __launch_bounds__(256) void k_conv_w2(const float* __restrict__ w2, u16* __restrict__ w2t) {
    int i = blockIdx.x * 256 + threadIdx.x;            // < E*O*H = 1M
    int h = i & 511, o = (i >> 9) & 255, e = i >> 17;
    w2t[i] = f2bf(w2[((size_t)e << 17) + ((size_t)h << 8) + o]);
}

// ---------------- gating ----------------
__global__ __launch_bounds__(256) void k_gating(const float* __restrict__ x,
                                                const float* __restrict__ gw,
                                                const float* __restrict__ gb,
                                                float* __restrict__ wt,
                                                double* __restrict__ part) {
    __shared__ float gws[DD * EE];
    __shared__ float gbs[EE];
    __shared__ double red[256];
    int tid = threadIdx.x;
    for (int i = tid; i < DD * EE; i += 256) gws[i] = gw[i];
    if (tid < EE) gbs[tid] = gb[tid];
    __syncthreads();

    int t = blockIdx.x * 256 + tid;
    double l[EE];
#pragma unroll
    for (int e = 0; e < EE; ++e) l[e] = (double)gbs[e];

    const f32x4* xr = (const f32x4*)(x + (size_t)t * DD);
    for (int d4 = 0; d4 < DD / 4; ++d4) {
        f32x4 xv = xr[d4];
#pragma unroll
        for (int j = 0; j < 4; ++j) {
            double xs = (double)xv[j];
            int d = d4 * 4 + j;
#pragma unroll
            for (int e = 0; e < EE; ++e) l[e] += xs * (double)gws[d * EE + e];
        }
    }
    double mx = l[0];
#pragma unroll
    for (int e = 1; e < EE; ++e) mx = l[e] > mx ? l[e] : mx;
    double p[EE], s = 0.0;
#pragma unroll
    for (int e = 0; e < EE; ++e) { p[e] = exp(l[e] - mx); s += p[e]; }
    double inv = 1.0 / s;
    double ent = 0.0;
#pragma unroll
    for (int e = 0; e < EE; ++e) { p[e] *= inv; ent += p[e] * log(p[e] + 1e-8); }

    bool mask[EE];
#pragma unroll
    for (int e = 0; e < EE; ++e) {
        double c = 0.0; int rk = 0;
#pragma unroll
        for (int f = 0; f < EE; ++f) {
            bool before = (p[f] > p[e]) || (p[f] == p[e] && f < e);
            if (before) { c += p[f]; rk++; }
        }
        c += p[e];
        mask[e] = (c <= 0.7) || (rk == 0);
    }
    double ms = 0.0;
#pragma unroll
    for (int e = 0; e < EE; ++e) if (mask[e]) ms += p[e];
    double inv2 = 1.0 / ms;
#pragma unroll
    for (int e = 0; e < EE; ++e) wt[(size_t)e * TT + t] = (float)(mask[e] ? p[e] * inv2 : 0.0);

    red[tid] = -ent;
    __syncthreads();
    for (int st = 128; st > 0; st >>= 1) {
        if (tid < st) red[tid] += red[tid + st];
        __syncthreads();
    }
    if (tid == 0) part[blockIdx.x] = red[0];
}

__global__ __launch_bounds__(256) void k_final(const double* __restrict__ part, float* __restrict__ loss) {
    __shared__ double red[256];
    int tid = threadIdx.x;
    red[tid] = part[tid];
    __syncthreads();
    for (int st = 128; st > 0; st >>= 1) {
        if (tid < st) red[tid] += red[tid + st];
        __syncthreads();
    }
    if (tid == 0) loss[0] = (float)(red[0] / (double)TT);
}

// ---------------- fused MoE MLP (v4: 8 waves, 32x32x16 MFMA) ----------------
// 64 tokens/block, 512 threads (8 waves). 16 chunks of 256 h (e = c>>1).
// G1: wave owns 32 h-rows: hf[t] (t = tok halves), A=W1 global, B=Xs LDS.
// G2: wave owns 32 o-cols:  oacc[t], A=Hs LDS, B=W2 global.
// LDS = 32K Xs + 32K Hs + 2K wts = 66K -> 2 blocks/CU; VGPR<=128 -> 16 waves/CU.
__global__ __launch_bounds__(512, 4) void k_moe(const float* __restrict__ x,
                                                const u16* __restrict__ w1t,
                                                const u16* __restrict__ w2t,
                                                const float* __restrict__ b1,
                                                const float* __restrict__ b2,
                                                const float* __restrict__ wtg,
                                                float* __restrict__ out) {
    __shared__ __align__(16) unsigned char smem[67584];
    unsigned char* Xs = smem;                     // 64 rows x 512B (bf16, swizzled)
    unsigned char* Hs = smem + 32768;             // 64 rows x 512B (bf16, swizzled)
    float* wts = (float*)(smem + 65536);          // [E][64] f32

    const int tid = threadIdx.x;                  // 0..511
    const int wid = tid >> 6;                     // 0..7
    const int lane = tid & 63;
    const int l31 = lane & 31;
    const int lg2 = lane >> 5;                    // 0..1
    const int t0 = blockIdx.x * 64;

    // stage X tile: f32 -> bf16, swizzle ^((row&15)<<4), rows = 512B
    {
        const f32x4* xsrc = (const f32x4*)(x + (size_t)t0 * DD);
#pragma unroll
        for (int i = 0; i < 4; ++i) {
            int L = i * 8192 + tid * 16;          // byte offset in bf16 tile
            f32x4 a = xsrc[L >> 3];
            f32x4 b = xsrc[(L >> 3) + 1];
            u32x4 o;
            o.x = (u32)f2bf(a[0]) | ((u32)f2bf(a[1]) << 16);
            o.y = (u32)f2bf(a[2]) | ((u32)f2bf(a[3]) << 16);
            o.z = (u32)f2bf(b[0]) | ((u32)f2bf(b[1]) << 16);
            o.w = (u32)f2bf(b[2]) | ((u32)f2bf(b[3]) << 16);
            int row = L >> 9;
            *(u32x4*)(Xs + (L ^ ((row & 15) << 4))) = o;
        }
    }
    // wts[e][tok]: wave wid loads expert wid
    wts[wid * 64 + lane] = wtg[(size_t)wid * TT + t0 + lane];
    __syncthreads();

    f32x16 oacc[2];
    oacc[0] = (f32x16)0.0f;
    oacc[1] = (f32x16)0.0f;

#pragma unroll 1
    for (int c = 0; c < 16; ++c) {
        const int e = c >> 1;
        // ---- G1: hf[t][reg] = H^T tile: rows h = wid*32 + crow(reg,lg2), cols tok
        f32x16 hf[2];
        hf[0] = (f32x16)0.0f;
        hf[1] = (f32x16)0.0f;
        const u16* w1p = w1t + ((size_t)(c * 256 + wid * 32 + l31)) * DD + lg2 * 8;
#pragma unroll 2
        for (int ks = 0; ks < 16; ++ks) {
            bf16x8 a = ld_frag(w1p + ks * 16);
#pragma unroll
            for (int t = 0; t < 2; ++t) {
                int tok = t * 32 + l31;
                int byt = tok * 512 + ks * 32 + lg2 * 16;
                bf16x8 b = ld_frag(Xs + (byt ^ ((tok & 15) << 4)));
                hf[t] = __builtin_amdgcn_mfma_f32_32x32x16_bf16(a, b, hf[t], 0, 0, 0);
            }
        }
        // epilogue: +b1, gelu, *wgt, pack -> Hs
        f32x4 bbv[4];
        {
            const float* b1p = b1 + c * 256 + wid * 32 + lg2 * 4;
#pragma unroll
            for (int q = 0; q < 4; ++q) bbv[q] = *(const f32x4*)(b1p + q * 8);
        }
#pragma unroll
        for (int t = 0; t < 2; ++t) {
            int tok = t * 32 + l31;
            float wgt = wts[e * 64 + tok];
#pragma unroll
            for (int q = 0; q < 4; ++q) {
                float g[4];
#pragma unroll
                for (int r = 0; r < 4; ++r) {
                    float v = hf[t][q * 4 + r] + bbv[q][r];
                    g[r] = gelu_fast(v) * wgt;
                }
                u32x2 pk;
                pk.x = (u32)f2bf(g[0]) | ((u32)f2bf(g[1]) << 16);
                pk.y = (u32)f2bf(g[2]) | ((u32)f2bf(g[3]) << 16);
                int hl = wid * 32 + q * 8 + lg2 * 4;      // h within chunk [0,256)
                int byt = tok * 512 + hl * 2;
                *(u32x2*)(Hs + (byt ^ ((tok & 15) << 4))) = pk;
            }
        }
        __syncthreads();
        // ---- G2: oacc[t] += Hs[tok][k] * W2[k][o], o = wid*32 + l31, K = 256 chunk
        const u16* w2p = w2t + ((size_t)(e * OO + wid * 32 + l31)) * HH + (c & 1) * 256 + lg2 * 8;
#pragma unroll 2
        for (int ks = 0; ks < 16; ++ks) {
            bf16x8 bw = ld_frag(w2p + ks * 16);
#pragma unroll
            for (int t = 0; t < 2; ++t) {
                int tok = t * 32 + l31;
                int byt = tok * 512 + ks * 32 + lg2 * 16;
                bf16x8 ah = ld_frag(Hs + (byt ^ ((tok & 15) << 4)));
                oacc[t] = __builtin_amdgcn_mfma_f32_32x32x16_bf16(ah, bw, oacc[t], 0, 0, 0);
            }
        }
        __syncthreads();
    }

    // epilogue: add sum_e wts[e][tok]*b2[e][o], store
    {
        int o = wid * 32 + l31;
        float b2v[EE];
#pragma unroll
        for (int e = 0; e < EE; ++e) b2v[e] = b2[e * OO + o];
#pragma unroll
        for (int t = 0; t < 2; ++t) {
#pragma unroll
            for (int r = 0; r < 16; ++r) {
                int tok = t * 32 + (r & 3) + 8 * (r >> 2) + 4 * lg2;
                float wb = 0.f;
#pragma unroll
                for (int e = 0; e < EE; ++e) wb += wts[e * 64 + tok] * b2v[e];
                out[(size_t)(t0 + tok) * OO + o] = oacc[t][r] + wb;
            }
        }
    }
}

extern "C" void kernel_launch(void* const* d_in, const int* in_sizes, int n_in,
                              void* d_out, int out_size, void* d_ws, size_t ws_size,
                              hipStream_t stream) {
    const float* x  = (const float*)d_in[0];
    const float* gw = (const float*)d_in[1];
    const float* gb = (const float*)d_in[2];
    const float* w1 = (const float*)d_in[3];
    const float* b1 = (const float*)d_in[4];
    const float* w2 = (const float*)d_in[5];
    const float* b2 = (const float*)d_in[6];
    float* out = (float*)d_out;

    char* ws = (char*)d_ws;
    u16* w1t    = (u16*)(ws);                    // 2 MB
    u16* w2t    = (u16*)(ws + 2097152);          // 2 MB
    float* wt   = (float*)(ws + 4194304);        // 2 MB ([E][T])
    double* prt = (double*)(ws + 6291456);       // 2 KB

    k_conv_w1<<<(EE * HH * DD) / 256, 256, 0, stream>>>(w1, w1t);
    k_conv_w2<<<(EE * OO * HH) / 256, 256, 0, stream>>>(w2, w2t);
    k_gating<<<TT / 256, 256, 0, stream>>>(x, gw, gb, wt, prt);
    k_moe<<<TT / 64, 512, 0, stream>>>(x, w1t, w2t, b1, b2, wt, out);
    k_final<<<1, 256, 0, stream>>>(prt, out + (size_t)TT * OO);
}